// Round 2
// baseline (7600.280 us; speedup 1.0000x reference)
//
#include <hip/hip_runtime.h>

// EncoderLSTMContinuous v5: MT=16, 512 WGs x 512 thr, 2 WGs/CU (16 waves/CU).
// v4 post-mortem: __launch_bounds__(1024,4) + dynamic LDS (invisible to the
// occupancy heuristic) made the compiler target 8 waves/SIMD -> 64 VGPR ->
// sweepW double-buffer spilled to scratch (WRITE_SIZE rose to 1.13GB), dur
// 4.26->6.49ms. v5 keeps v3's exact per-wave structure and launch bounds
// (512,2) -- empirically 128 VGPR, no spills -- and gets 4 waves/SIMD via
// HARDWARE residency: MT=16 halves LDS to 77.6KB so 2 WGs co-reside.
// Per-wave acc arrays halve (one 16-row MFMA tile), weight sweeps unchanged.
// Two WGs/CU read the same weight stream (L1 sharing) and overlap barriers.
// Keeps v4's s_y LDS output staging (full 128B-line nt stores).

typedef _Float16 half_t;
typedef _Float16 half8 __attribute__((ext_vector_type(8)));
typedef _Float16 half4v __attribute__((ext_vector_type(4)));
typedef float float4_ __attribute__((ext_vector_type(4)));

#define UNITS 512
#define IN_DIM 1024
#define NROWS 8192
#define DEPTH 32
#define ZK 256
#define MT 16
#define PITCH (UNITS + 8)    // 520 halves; 260 dwords -> 2-way (free) on b128
#define XPITCH (IN_DIM + 8)

__device__ inline float4_ mfma16(half8 a, half8 b, float4_ c) {
  // D[m][n]: m=(lane>>4)*4+reg, n=lane&15. A[m=lane&15][k=(lane>>4)*8+j], B[k][n=lane&15].
  return __builtin_amdgcn_mfma_f32_16x16x32_f16(a, b, c, 0, 0, 0);
}
__device__ inline float fast_sigmoid(float x) {
  return __builtin_amdgcn_rcpf(1.0f + __builtin_amdgcn_exp2f(-1.4426950408889634f * x));
}
__device__ inline float fast_tanh(float x) {
  return 2.0f * __builtin_amdgcn_rcpf(1.0f + __builtin_amdgcn_exp2f(-2.8853900817779268f * x)) - 1.0f;
}

// acc[i]: reg r -> wcol = colbase + blk(i)*16 + q*4 + r ; lane c16 -> actrow c16.
// wbase = W_T + (colbase + c16)*UNITS + q*8 ; abase = buf + c16*PITCH + q*8.
// Register double-buffer: iteration kk prefetches kk+1's weights before MFMAs.
template<int NM, class OffF>
__device__ inline void sweepW(const half_t* __restrict__ wbase, OffF off,
                              const half_t* __restrict__ abase,
                              float4_ (&acc)[NM]) {
#pragma unroll
  for (int i = 0; i < NM; ++i) acc[i] = {0.f, 0.f, 0.f, 0.f};
  half8 w0[2][NM], w1[2][NM];
#pragma unroll
  for (int i = 0; i < NM; ++i) {
    w0[0][i] = *(const half8*)(wbase + off(i));
    w1[0][i] = *(const half8*)(wbase + off(i) + 32);
  }
#pragma unroll
  for (int kk = 0; kk < 8; ++kk) {
    const int cur = kk & 1, nxt = cur ^ 1;
    const int knext = ((kk + 1) & 7) * 64;  // wraps to 0 on last iter (L1-hot, harmless)
#pragma unroll
    for (int i = 0; i < NM; ++i) {
      w0[nxt][i] = *(const half8*)(wbase + off(i) + knext);
      w1[nxt][i] = *(const half8*)(wbase + off(i) + knext + 32);
    }
    const int k0 = kk * 64;
    half8 a0 = *(const half8*)(abase + k0);
    half8 a1 = *(const half8*)(abase + k0 + 32);
#pragma unroll
    for (int i = 0; i < NM; ++i) {
      acc[i] = mfma16(w0[cur][i], a0, acc[i]);
      acc[i] = mfma16(w1[cur][i], a1, acc[i]);
    }
  }
}

// ---- old-orientation helper for xh_kernel (acts=A, weights=B)
template<int NB, int K, int AP, class OffF>
__device__ inline void stage_gemm(const half_t* __restrict__ bbase, OffF off,
                                  const half_t* __restrict__ A, int q, int c16,
                                  float4_ (&acc)[NB][2]) {
#pragma unroll
  for (int nb = 0; nb < NB; ++nb) {
    acc[nb][0] = {0.f, 0.f, 0.f, 0.f};
    acc[nb][1] = {0.f, 0.f, 0.f, 0.f};
  }
  for (int k0 = 0; k0 < K; k0 += 64) {
    const half_t* ap = A + c16 * AP + k0 + q * 8;
    half8 a00 = *(const half8*)(ap);
    half8 a01 = *(const half8*)(ap + 32);
    half8 a10 = *(const half8*)(ap + 16 * AP);
    half8 a11 = *(const half8*)(ap + 16 * AP + 32);
#pragma unroll
    for (int nb = 0; nb < NB; ++nb) {
      const half_t* bp = bbase + off(nb) + k0;
      half8 b0 = *(const half8*)(bp);
      half8 b1 = *(const half8*)(bp + 32);
      acc[nb][0] = mfma16(a00, b0, acc[nb][0]);
      acc[nb][0] = mfma16(a01, b1, acc[nb][0]);
      acc[nb][1] = mfma16(a10, b0, acc[nb][1]);
      acc[nb][1] = mfma16(a11, b1, acc[nb][1]);
    }
  }
}

// ---- prep: fp32 [R][C] -> fp16 [C][R] tiled transpose-convert
__global__ void transpose_convert(const float* __restrict__ in, half_t* __restrict__ out,
                                  int R, int C) {
  __shared__ float tile[32][33];
  int c0 = blockIdx.x * 32, r0 = blockIdx.y * 32;
  int tx = threadIdx.x, ty = threadIdx.y;
#pragma unroll
  for (int i = 0; i < 32; i += 8)
    tile[ty + i][tx] = in[(size_t)(r0 + ty + i) * C + c0 + tx];
  __syncthreads();
#pragma unroll
  for (int i = 0; i < 32; i += 8)
    out[(size_t)(c0 + ty + i) * R + r0 + tx] = (half_t)tile[tx][ty + i];
}

// ---- one-time xh = x @ h_W + h_b  (fp16 out, h_b folded in)
__global__ __launch_bounds__(512, 2) void xh_kernel(
    const float* __restrict__ x, const half_t* __restrict__ hW_T,
    const float* __restrict__ h_b, half_t* __restrict__ xh_g) {
  extern __shared__ half_t sx[];
  const int tid = threadIdx.x;
  const int w = tid >> 6, l = tid & 63, q = l >> 4, c16 = l & 15;
  const int row0 = blockIdx.x * 32;
  for (int it = tid; it < 32 * IN_DIM / 4; it += 512) {
    int r = it >> 8;
    int c = (it & 255) * 4;
    float4_ v = __builtin_nontemporal_load((const float4_*)(x + (size_t)(row0 + r) * IN_DIM + c));
    half4v hv;
    hv[0] = (half_t)v[0]; hv[1] = (half_t)v[1]; hv[2] = (half_t)v[2]; hv[3] = (half_t)v[3];
    *(half4v*)(sx + r * XPITCH + c) = hv;
  }
  __syncthreads();
  const int n0 = w * 64;
  float4_ acc[4][2];
  const half_t* bbase = hW_T + (size_t)(n0 + c16) * IN_DIM + q * 8;
  stage_gemm<4, IN_DIM, XPITCH>(bbase, [](int nb) { return nb * 16 * IN_DIM; }, sx, q, c16, acc);
#pragma unroll
  for (int nb = 0; nb < 4; ++nb)
#pragma unroll
    for (int mb = 0; mb < 2; ++mb)
#pragma unroll
      for (int r = 0; r < 4; ++r) {
        int row = mb * 16 + q * 4 + r;
        int col = n0 + nb * 16 + c16;
        xh_g[(size_t)(row0 + row) * UNITS + col] = (half_t)(acc[nb][mb][r] + h_b[col]);
      }
}

// ---- the persistent scan kernel (MT=16, 512 WGs, 8 waves each, 2 WGs/CU)
__global__ __launch_bounds__(512, 2) void lstm_main(
    const half_t* __restrict__ xh_g, const half_t* __restrict__ hU_T,
    const half_t* __restrict__ W4_T, const half_t* __restrict__ tW_T,
    const half_t* __restrict__ yW_T,
    const float* __restrict__ f_b, const float* __restrict__ i_b,
    const float* __restrict__ c_b, const float* __restrict__ o_b,
    const float* __restrict__ t_b, const float* __restrict__ y_b,
    const float* __restrict__ h0, float* __restrict__ out) {
  extern __shared__ half_t smem[];
  half_t* bufA = smem;                 // state -> (o*h1) -> state
  half_t* bufB = smem + MT * PITCH;    // h -> t
  half_t* s_xh = smem + 2 * MT * PITCH;                 // xh, persistent all 32 steps
  float* s_bias = (float*)(smem + 3 * MT * PITCH);      // f,i,c,o,t (512 ea) + y (256)
  float* s_fb = s_bias;
  float* s_ib = s_bias + 512;
  float* s_cb = s_bias + 1024;
  float* s_ob = s_bias + 1536;
  float* s_tb = s_bias + 2048;
  float* s_yb = s_bias + 2560;
  float* s_y  = s_bias + 2816;         // [MT][ZK] fp32 output staging (16KB)

  const int tid = threadIdx.x;
  const int w = tid >> 6, l = tid & 63, q = l >> 4, c16 = l & 15;
  const int row0 = blockIdx.x * MT;

  // init bufA = broadcast h0 (fp16); s_xh from xh_g; biases
  for (int it = tid; it < MT * UNITS / 8; it += 512) {
    int r = it >> 6;
    int c = (it & 63) * 8;
    float4_ v0 = *(const float4_*)(h0 + c);
    float4_ v1 = *(const float4_*)(h0 + c + 4);
    half8 hv;
#pragma unroll
    for (int j = 0; j < 4; ++j) { hv[j] = (half_t)v0[j]; hv[4 + j] = (half_t)v1[j]; }
    *(half8*)(bufA + r * PITCH + c) = hv;
    *(half8*)(s_xh + r * PITCH + c) = *(const half8*)(xh_g + (size_t)(row0 + r) * UNITS + c);
  }
  if (tid < 512) {
    s_fb[tid] = f_b[tid]; s_ib[tid] = i_b[tid]; s_cb[tid] = c_b[tid]; s_ob[tid] = o_b[tid];
    s_tb[tid] = t_b[tid];
    if (tid < 256) s_yb[tid] = y_b[tid];
  }
  // state registers: row = c16, col = hh*256 + w*32 + cm*16 + q*4 + r
  half4v state_r[2][2];
#pragma unroll
  for (int hh = 0; hh < 2; ++hh)
#pragma unroll
    for (int cm = 0; cm < 2; ++cm) {
      int col0 = hh * 256 + w * 32 + cm * 16 + q * 4;
      float4_ v = *(const float4_*)(h0 + col0);
      half4v s4;
#pragma unroll
      for (int r = 0; r < 4; ++r) s4[r] = (half_t)v[r];
      state_r[hh][cm] = s4;
    }
  __syncthreads();

  for (int s = 0; s < DEPTH; ++s) {
    // ---- stage 1: h = tanh(xh + state @ h_U) : read bufA -> write bufB
    {
      float4_ acc[4];
      const half_t* wb = hU_T + (size_t)(w * 64 + c16) * UNITS + q * 8;
      sweepW<4>(wb, [](int i) { return i * 16 * UNITS; }, bufA + c16 * PITCH + q * 8, acc);
#pragma unroll
      for (int cm = 0; cm < 4; ++cm) {
        int col0 = w * 64 + cm * 16 + q * 4;
        half4v xh4 = *(const half4v*)(s_xh + c16 * PITCH + col0);
        half4v hv;
#pragma unroll
        for (int r = 0; r < 4; ++r) hv[r] = (half_t)fast_tanh(acc[cm][r] + (float)xh4[r]);
        *(half4v*)(bufB + c16 * PITCH + col0) = hv;
      }
    }
    __syncthreads();
    // ---- stage 2: gates from h (bufB); two column-half sweeps; write o*h1 -> bufA
#pragma unroll 1
    for (int hh = 0; hh < 2; ++hh) {
      float4_ acc[8];  // i = mat*2 + cm
      const int colbase = hh * 256 + w * 32;
      const half_t* wb = W4_T + (size_t)(colbase + c16) * UNITS + q * 8;
      sweepW<8>(wb, [](int i) { return (i >> 1) * (UNITS * UNITS) + (i & 1) * 16 * UNITS; },
                bufB + c16 * PITCH + q * 8, acc);
#pragma unroll
      for (int cm = 0; cm < 2; ++cm) {
        int col0 = colbase + cm * 16 + q * 4;
        float4_ fb4 = *(const float4_*)(s_fb + col0);
        float4_ ib4 = *(const float4_*)(s_ib + col0);
        float4_ cb4 = *(const float4_*)(s_cb + col0);
        float4_ ob4 = *(const float4_*)(s_ob + col0);
        half4v hp = state_r[hh][cm];
        half4v h1v, sbv;
#pragma unroll
        for (int r = 0; r < 4; ++r) {
          float gf = fast_sigmoid(acc[0 * 2 + cm][r] + fb4[r]);
          float gi = fast_sigmoid(acc[1 * 2 + cm][r] + ib4[r]);
          float gc = fast_tanh   (acc[2 * 2 + cm][r] + cb4[r]);
          float go = fast_sigmoid(acc[3 * 2 + cm][r] + ob4[r]);
          float h1 = (float)hp[r] * gf + gc * gi;
          h1v[r] = (half_t)h1;
          sbv[r] = (half_t)(go * h1);
        }
        state_r[hh][cm] = h1v;
        *(half4v*)(bufA + c16 * PITCH + col0) = sbv;
      }
    }
    __syncthreads();
    // ---- stage 3: t = tanh((o*h1) @ t_W + t_b) : read bufA -> write bufB
    {
      float4_ acc[4];
      const half_t* wb = tW_T + (size_t)(w * 64 + c16) * UNITS + q * 8;
      sweepW<4>(wb, [](int i) { return i * 16 * UNITS; }, bufA + c16 * PITCH + q * 8, acc);
#pragma unroll
      for (int cm = 0; cm < 4; ++cm) {
        int col0 = w * 64 + cm * 16 + q * 4;
        float4_ tb4 = *(const float4_*)(s_tb + col0);
        half4v hv;
#pragma unroll
        for (int r = 0; r < 4; ++r) hv[r] = (half_t)fast_tanh(acc[cm][r] + tb4[r]);
        *(half4v*)(bufB + c16 * PITCH + col0) = hv;
      }
    }
    __syncthreads();
    // ---- stage 4: y = tanh(t @ y_W + y_b) -> s_y (LDS); state regs -> bufA
    {
      float4_ acc[2];
      const half_t* wb = yW_T + (size_t)(w * 32 + c16) * UNITS + q * 8;
      sweepW<2>(wb, [](int i) { return i * 16 * UNITS; }, bufB + c16 * PITCH + q * 8, acc);
#pragma unroll
      for (int cm = 0; cm < 2; ++cm) {
        const int col0 = w * 32 + cm * 16 + q * 4;
        float4_ yb4 = *(const float4_*)(s_yb + col0);
        float4_ yv;
#pragma unroll
        for (int r = 0; r < 4; ++r) yv[r] = fast_tanh(acc[cm][r] + yb4[r]);
        *(float4_*)(s_y + c16 * ZK + col0) = yv;
      }
#pragma unroll
      for (int hh = 0; hh < 2; ++hh)
#pragma unroll
        for (int cm = 0; cm < 2; ++cm) {
          int sc0 = hh * 256 + w * 32 + cm * 16 + q * 4;
          *(half4v*)(bufA + c16 * PITCH + sc0) = state_r[hh][cm];
        }
    }
    __syncthreads();
    // ---- copy-out: one full 1KB row per wave-instr -> full 128B lines, nt.
    // Overlaps next step's stage 1 (disjoint LDS: s_y vs bufA/bufB/s_xh).
    for (int it = tid; it < MT * ZK / 4; it += 512) {
      int r = it >> 6;
      int ch = (it & 63) * 4;
      float4_ v = *(const float4_*)(s_y + r * ZK + ch);
      __builtin_nontemporal_store(v, (float4_*)(out + ((size_t)(row0 + r) * DEPTH + s) * ZK + ch));
    }
  }
}

extern "C" void kernel_launch(void* const* d_in, const int* in_sizes, int n_in,
                              void* d_out, int out_size, void* d_ws, size_t ws_size,
                              hipStream_t stream) {
  (void)in_sizes; (void)n_in; (void)out_size; (void)ws_size;
  const float* x   = (const float*)d_in[0];
  const float* h_W = (const float*)d_in[1];
  const float* h_U = (const float*)d_in[2];
  const float* h_b = (const float*)d_in[3];
  const float* f_W = (const float*)d_in[4];
  const float* f_b = (const float*)d_in[5];
  const float* i_W = (const float*)d_in[6];
  const float* i_b = (const float*)d_in[7];
  const float* c_W = (const float*)d_in[8];
  const float* c_b = (const float*)d_in[9];
  const float* o_W = (const float*)d_in[10];
  const float* o_b = (const float*)d_in[11];
  const float* t_W = (const float*)d_in[12];
  const float* t_b = (const float*)d_in[13];
  const float* y_W = (const float*)d_in[14];
  const float* y_b = (const float*)d_in[15];
  const float* h0  = (const float*)d_in[16];
  float* out = (float*)d_out;

  half_t* ws   = (half_t*)d_ws;
  half_t* hW_T = ws;                                   // [512][1024]
  half_t* hU_T = hW_T + (size_t)UNITS * IN_DIM;        // [512][512]
  half_t* W4_T = hU_T + (size_t)UNITS * UNITS;         // [2048][512] f,i,c,o
  half_t* tW_T = W4_T + (size_t)4 * UNITS * UNITS;     // [512][512]
  half_t* yW_T = tW_T + (size_t)UNITS * UNITS;         // [256][512]
  half_t* xh_g = yW_T + (size_t)ZK * UNITS;            // [8192][512]

  // bufA,bufB,s_xh (49,920B) + biases (11,264B) + s_y (16,384B) = 77,568B
  // => 2 WGs/CU (155,136B <= 160KB)
  const int lds_main = 3 * MT * PITCH * 2 + 2816 * 4 + MT * ZK * 4;
  hipFuncSetAttribute((const void*)xh_kernel, hipFuncAttributeMaxDynamicSharedMemorySize,
                      32 * XPITCH * 2);
  hipFuncSetAttribute((const void*)lstm_main, hipFuncAttributeMaxDynamicSharedMemorySize,
                      lds_main);

  dim3 tb(32, 8);
  hipLaunchKernelGGL(transpose_convert, dim3(UNITS / 32, IN_DIM / 32), tb, 0, stream,
                     h_W, hW_T, IN_DIM, UNITS);
  hipLaunchKernelGGL(transpose_convert, dim3(UNITS / 32, UNITS / 32), tb, 0, stream,
                     h_U, hU_T, UNITS, UNITS);
  hipLaunchKernelGGL(transpose_convert, dim3(UNITS / 32, UNITS / 32), tb, 0, stream,
                     f_W, W4_T + 0 * (size_t)UNITS * UNITS, UNITS, UNITS);
  hipLaunchKernelGGL(transpose_convert, dim3(UNITS / 32, UNITS / 32), tb, 0, stream,
                     i_W, W4_T + 1 * (size_t)UNITS * UNITS, UNITS, UNITS);
  hipLaunchKernelGGL(transpose_convert, dim3(UNITS / 32, UNITS / 32), tb, 0, stream,
                     c_W, W4_T + 2 * (size_t)UNITS * UNITS, UNITS, UNITS);
  hipLaunchKernelGGL(transpose_convert, dim3(UNITS / 32, UNITS / 32), tb, 0, stream,
                     o_W, W4_T + 3 * (size_t)UNITS * UNITS, UNITS, UNITS);
  hipLaunchKernelGGL(transpose_convert, dim3(UNITS / 32, UNITS / 32), tb, 0, stream,
                     t_W, tW_T, UNITS, UNITS);
  hipLaunchKernelGGL(transpose_convert, dim3(ZK / 32, UNITS / 32), tb, 0, stream,
                     y_W, yW_T, UNITS, ZK);
  hipLaunchKernelGGL(xh_kernel, dim3(NROWS / 32), dim3(512), 32 * XPITCH * 2, stream,
                     x, hW_T, h_b, xh_g);
  hipLaunchKernelGGL(lstm_main, dim3(NROWS / MT), dim3(512), lds_main, stream,
                     xh_g, hU_T, W4_T, tW_T, yW_T, f_b, i_b, c_b, o_b, t_b, y_b, h0, out);
}

// Round 3
// 4322.243 us; speedup vs baseline: 1.7584x; 1.7584x over previous
//
#include <hip/hip_runtime.h>

// EncoderLSTMContinuous v6: v3 base (MT=32, 256 WGs x 512 thr, 1 WG/CU,
// VGPR=128 known-good) + prefetch-distance-2 weight pipeline in sweepW.
// v4/v5 post-mortem: both "more waves/SIMD" attempts failed mechanically
// (v4: launch_bounds(1024,4) strangled allocator to 64 VGPR -> spills;
// v5: 2 WGs x 77.6KB never co-resided, occupancy stayed 21% -> 2 sequential
// rounds, 2x weight work). v6 spends the idle VGPR headroom (cap 256 at
// 2 waves/SIMD, only 128 used) on in-flight weight loads instead of waves:
// 3-slot rotating register buffer, loads for kk+2 issued before kk's MFMAs.
// Coverage 2x MFMA phase (~160-320 cyc wall) vs L2 ~200 / L3 ~400-900 cyc.
// All indices compile-time (full unroll; wrap prefetch guarded by kk<6).
// Weight traffic per CU unchanged (one 3.25MB sweep/step). Everything else
// byte-identical to the 4.26ms v3.

typedef _Float16 half_t;
typedef _Float16 half8 __attribute__((ext_vector_type(8)));
typedef _Float16 half4v __attribute__((ext_vector_type(4)));
typedef float float4_ __attribute__((ext_vector_type(4)));

#define UNITS 512
#define IN_DIM 1024
#define NROWS 8192
#define DEPTH 32
#define ZK 256
#define MT 32
#define PITCH (UNITS + 8)    // 520 halves; 260 dwords -> 2-way (free) on b128
#define XPITCH (IN_DIM + 8)

__device__ inline float4_ mfma16(half8 a, half8 b, float4_ c) {
  // D[m][n]: m=(lane>>4)*4+reg, n=lane&15. A[m=lane&15][k=(lane>>4)*8+j], B[k][n=lane&15].
  return __builtin_amdgcn_mfma_f32_16x16x32_f16(a, b, c, 0, 0, 0);
}
__device__ inline float fast_sigmoid(float x) {
  return __builtin_amdgcn_rcpf(1.0f + __builtin_amdgcn_exp2f(-1.4426950408889634f * x));
}
__device__ inline float fast_tanh(float x) {
  return 2.0f * __builtin_amdgcn_rcpf(1.0f + __builtin_amdgcn_exp2f(-2.8853900817779268f * x)) - 1.0f;
}

// acc[i][rb]: reg r -> wcol = colbase + blk(i)*16 + q*4 + r ; lane c16 -> actrow rb*16+c16.
// wbase = W_T + (colbase + c16)*UNITS + q*8 ; abase = buf + c16*PITCH + q*8.
// 3-slot rotating register buffer, prefetch distance 2: iteration kk issues
// kk+2's weight loads before kk's MFMAs. Slots indexed kk%3 / (kk+2)%3 --
// compile-time after full unroll (rule: no runtime-indexed ext_vector arrays).
template<int NM, class OffF>
__device__ inline void sweepW(const half_t* __restrict__ wbase, OffF off,
                              const half_t* __restrict__ abase,
                              float4_ (&acc)[NM][2]) {
#pragma unroll
  for (int i = 0; i < NM; ++i) {
    acc[i][0] = {0.f, 0.f, 0.f, 0.f};
    acc[i][1] = {0.f, 0.f, 0.f, 0.f};
  }
  half8 w0[3][NM], w1[3][NM];
#pragma unroll
  for (int sl = 0; sl < 2; ++sl)
#pragma unroll
    for (int i = 0; i < NM; ++i) {
      w0[sl][i] = *(const half8*)(wbase + off(i) + sl * 64);
      w1[sl][i] = *(const half8*)(wbase + off(i) + sl * 64 + 32);
    }
#pragma unroll
  for (int kk = 0; kk < 8; ++kk) {
    const int cur = kk % 3;
    if (kk < 6) {                      // folds at unroll time; no wrap reloads
      const int pf = (kk + 2) % 3;
      const int kpf = (kk + 2) * 64;
#pragma unroll
      for (int i = 0; i < NM; ++i) {
        w0[pf][i] = *(const half8*)(wbase + off(i) + kpf);
        w1[pf][i] = *(const half8*)(wbase + off(i) + kpf + 32);
      }
    }
    const int k0 = kk * 64;
    half8 a00 = *(const half8*)(abase + k0);
    half8 a01 = *(const half8*)(abase + k0 + 32);
    half8 a10 = *(const half8*)(abase + 16 * PITCH + k0);
    half8 a11 = *(const half8*)(abase + 16 * PITCH + k0 + 32);
#pragma unroll
    for (int i = 0; i < NM; ++i) {
      acc[i][0] = mfma16(w0[cur][i], a00, acc[i][0]);
      acc[i][0] = mfma16(w1[cur][i], a01, acc[i][0]);
      acc[i][1] = mfma16(w0[cur][i], a10, acc[i][1]);
      acc[i][1] = mfma16(w1[cur][i], a11, acc[i][1]);
    }
  }
}

// ---- old-orientation helper for xh_kernel (acts=A, weights=B)
template<int NB, int K, int AP, class OffF>
__device__ inline void stage_gemm(const half_t* __restrict__ bbase, OffF off,
                                  const half_t* __restrict__ A, int q, int c16,
                                  float4_ (&acc)[NB][2]) {
#pragma unroll
  for (int nb = 0; nb < NB; ++nb) {
    acc[nb][0] = {0.f, 0.f, 0.f, 0.f};
    acc[nb][1] = {0.f, 0.f, 0.f, 0.f};
  }
  for (int k0 = 0; k0 < K; k0 += 64) {
    const half_t* ap = A + c16 * AP + k0 + q * 8;
    half8 a00 = *(const half8*)(ap);
    half8 a01 = *(const half8*)(ap + 32);
    half8 a10 = *(const half8*)(ap + 16 * AP);
    half8 a11 = *(const half8*)(ap + 16 * AP + 32);
#pragma unroll
    for (int nb = 0; nb < NB; ++nb) {
      const half_t* bp = bbase + off(nb) + k0;
      half8 b0 = *(const half8*)(bp);
      half8 b1 = *(const half8*)(bp + 32);
      acc[nb][0] = mfma16(a00, b0, acc[nb][0]);
      acc[nb][0] = mfma16(a01, b1, acc[nb][0]);
      acc[nb][1] = mfma16(a10, b0, acc[nb][1]);
      acc[nb][1] = mfma16(a11, b1, acc[nb][1]);
    }
  }
}

// ---- prep: fp32 [R][C] -> fp16 [C][R] tiled transpose-convert
__global__ void transpose_convert(const float* __restrict__ in, half_t* __restrict__ out,
                                  int R, int C) {
  __shared__ float tile[32][33];
  int c0 = blockIdx.x * 32, r0 = blockIdx.y * 32;
  int tx = threadIdx.x, ty = threadIdx.y;
#pragma unroll
  for (int i = 0; i < 32; i += 8)
    tile[ty + i][tx] = in[(size_t)(r0 + ty + i) * C + c0 + tx];
  __syncthreads();
#pragma unroll
  for (int i = 0; i < 32; i += 8)
    out[(size_t)(c0 + ty + i) * R + r0 + tx] = (half_t)tile[tx][ty + i];
}

// ---- one-time xh = x @ h_W + h_b  (fp16 out, h_b folded in)
__global__ __launch_bounds__(512, 2) void xh_kernel(
    const float* __restrict__ x, const half_t* __restrict__ hW_T,
    const float* __restrict__ h_b, half_t* __restrict__ xh_g) {
  extern __shared__ half_t sx[];
  const int tid = threadIdx.x;
  const int w = tid >> 6, l = tid & 63, q = l >> 4, c16 = l & 15;
  const int row0 = blockIdx.x * 32;
  for (int it = tid; it < 32 * IN_DIM / 4; it += 512) {
    int r = it >> 8;
    int c = (it & 255) * 4;
    float4_ v = __builtin_nontemporal_load((const float4_*)(x + (size_t)(row0 + r) * IN_DIM + c));
    half4v hv;
    hv[0] = (half_t)v[0]; hv[1] = (half_t)v[1]; hv[2] = (half_t)v[2]; hv[3] = (half_t)v[3];
    *(half4v*)(sx + r * XPITCH + c) = hv;
  }
  __syncthreads();
  const int n0 = w * 64;
  float4_ acc[4][2];
  const half_t* bbase = hW_T + (size_t)(n0 + c16) * IN_DIM + q * 8;
  stage_gemm<4, IN_DIM, XPITCH>(bbase, [](int nb) { return nb * 16 * IN_DIM; }, sx, q, c16, acc);
#pragma unroll
  for (int nb = 0; nb < 4; ++nb)
#pragma unroll
    for (int mb = 0; mb < 2; ++mb)
#pragma unroll
      for (int r = 0; r < 4; ++r) {
        int row = mb * 16 + q * 4 + r;
        int col = n0 + nb * 16 + c16;
        xh_g[(size_t)(row0 + row) * UNITS + col] = (half_t)(acc[nb][mb][r] + h_b[col]);
      }
}

// ---- the persistent scan kernel (MT=32, 256 WGs, 8 waves each)
__global__ __launch_bounds__(512, 2) void lstm_main(
    const half_t* __restrict__ xh_g, const half_t* __restrict__ hU_T,
    const half_t* __restrict__ W4_T, const half_t* __restrict__ tW_T,
    const half_t* __restrict__ yW_T,
    const float* __restrict__ f_b, const float* __restrict__ i_b,
    const float* __restrict__ c_b, const float* __restrict__ o_b,
    const float* __restrict__ t_b, const float* __restrict__ y_b,
    const float* __restrict__ h0, float* __restrict__ out) {
  extern __shared__ half_t smem[];
  half_t* bufA = smem;                 // state -> (o*h1) -> state
  half_t* bufB = smem + MT * PITCH;    // h -> t
  half_t* s_xh = smem + 2 * MT * PITCH;                 // xh, persistent all 32 steps
  float* s_bias = (float*)(smem + 3 * MT * PITCH);      // f,i,c,o,t (512 ea) + y (256)
  float* s_fb = s_bias;
  float* s_ib = s_bias + 512;
  float* s_cb = s_bias + 1024;
  float* s_ob = s_bias + 1536;
  float* s_tb = s_bias + 2048;
  float* s_yb = s_bias + 2560;

  const int tid = threadIdx.x;
  const int w = tid >> 6, l = tid & 63, q = l >> 4, c16 = l & 15;
  const int row0 = blockIdx.x * MT;

  // init bufA = broadcast h0 (fp16); s_xh from xh_g; biases
  for (int it = tid; it < MT * UNITS / 8; it += 512) {
    int r = it >> 6;
    int c = (it & 63) * 8;
    float4_ v0 = *(const float4_*)(h0 + c);
    float4_ v1 = *(const float4_*)(h0 + c + 4);
    half8 hv;
#pragma unroll
    for (int j = 0; j < 4; ++j) { hv[j] = (half_t)v0[j]; hv[4 + j] = (half_t)v1[j]; }
    *(half8*)(bufA + r * PITCH + c) = hv;
    *(half8*)(s_xh + r * PITCH + c) = *(const half8*)(xh_g + (size_t)(row0 + r) * UNITS + c);
  }
  for (int it = tid; it < 512; it += 512) {
    s_fb[it] = f_b[it]; s_ib[it] = i_b[it]; s_cb[it] = c_b[it]; s_ob[it] = o_b[it];
    s_tb[it] = t_b[it];
    if (it < 256) s_yb[it] = y_b[it];
  }
  // state registers: row = rb*16 + c16, col = hh*256 + w*32 + cm*16 + q*4 + r
  half4v state_r[2][2][2];
#pragma unroll
  for (int hh = 0; hh < 2; ++hh)
#pragma unroll
    for (int cm = 0; cm < 2; ++cm) {
      int col0 = hh * 256 + w * 32 + cm * 16 + q * 4;
      float4_ v = *(const float4_*)(h0 + col0);
      half4v s4;
#pragma unroll
      for (int r = 0; r < 4; ++r) s4[r] = (half_t)v[r];
#pragma unroll
      for (int rb = 0; rb < 2; ++rb) state_r[hh][cm][rb] = s4;
    }
  __syncthreads();

  for (int s = 0; s < DEPTH; ++s) {
    // ---- stage 1: h = tanh(xh + state @ h_U) : read bufA -> write bufB
    {
      float4_ acc[4][2];
      const half_t* wb = hU_T + (size_t)(w * 64 + c16) * UNITS + q * 8;
      sweepW<4>(wb, [](int i) { return i * 16 * UNITS; }, bufA + c16 * PITCH + q * 8, acc);
#pragma unroll
      for (int cm = 0; cm < 4; ++cm) {
        int col0 = w * 64 + cm * 16 + q * 4;
#pragma unroll
        for (int rb = 0; rb < 2; ++rb) {
          int row = rb * 16 + c16;
          half4v xh4 = *(const half4v*)(s_xh + row * PITCH + col0);
          half4v hv;
#pragma unroll
          for (int r = 0; r < 4; ++r) hv[r] = (half_t)fast_tanh(acc[cm][rb][r] + (float)xh4[r]);
          *(half4v*)(bufB + row * PITCH + col0) = hv;
        }
      }
    }
    __syncthreads();
    // ---- stage 2: gates from h (bufB); two column-half sweeps; write o*h1 -> bufA
#pragma unroll 1
    for (int hh = 0; hh < 2; ++hh) {
      float4_ acc[8][2];  // i = mat*2 + cm
      const int colbase = hh * 256 + w * 32;
      const half_t* wb = W4_T + (size_t)(colbase + c16) * UNITS + q * 8;
      sweepW<8>(wb, [](int i) { return (i >> 1) * (UNITS * UNITS) + (i & 1) * 16 * UNITS; },
                bufB + c16 * PITCH + q * 8, acc);
#pragma unroll
      for (int cm = 0; cm < 2; ++cm) {
        int col0 = colbase + cm * 16 + q * 4;
        float4_ fb4 = *(const float4_*)(s_fb + col0);
        float4_ ib4 = *(const float4_*)(s_ib + col0);
        float4_ cb4 = *(const float4_*)(s_cb + col0);
        float4_ ob4 = *(const float4_*)(s_ob + col0);
#pragma unroll
        for (int rb = 0; rb < 2; ++rb) {
          int row = rb * 16 + c16;
          half4v hp = state_r[hh][cm][rb];
          half4v h1v, sbv;
#pragma unroll
          for (int r = 0; r < 4; ++r) {
            float gf = fast_sigmoid(acc[0 * 2 + cm][rb][r] + fb4[r]);
            float gi = fast_sigmoid(acc[1 * 2 + cm][rb][r] + ib4[r]);
            float gc = fast_tanh   (acc[2 * 2 + cm][rb][r] + cb4[r]);
            float go = fast_sigmoid(acc[3 * 2 + cm][rb][r] + ob4[r]);
            float h1 = (float)hp[r] * gf + gc * gi;
            h1v[r] = (half_t)h1;
            sbv[r] = (half_t)(go * h1);
          }
          state_r[hh][cm][rb] = h1v;
          *(half4v*)(bufA + row * PITCH + col0) = sbv;
        }
      }
    }
    __syncthreads();
    // ---- stage 3: t = tanh((o*h1) @ t_W + t_b) : read bufA -> write bufB
    {
      float4_ acc[4][2];
      const half_t* wb = tW_T + (size_t)(w * 64 + c16) * UNITS + q * 8;
      sweepW<4>(wb, [](int i) { return i * 16 * UNITS; }, bufA + c16 * PITCH + q * 8, acc);
#pragma unroll
      for (int cm = 0; cm < 4; ++cm) {
        int col0 = w * 64 + cm * 16 + q * 4;
        float4_ tb4 = *(const float4_*)(s_tb + col0);
#pragma unroll
        for (int rb = 0; rb < 2; ++rb) {
          int row = rb * 16 + c16;
          half4v hv;
#pragma unroll
          for (int r = 0; r < 4; ++r) hv[r] = (half_t)fast_tanh(acc[cm][rb][r] + tb4[r]);
          *(half4v*)(bufB + row * PITCH + col0) = hv;
        }
      }
    }
    __syncthreads();
    // ---- stage 4: y = tanh(t @ y_W + y_b) -> nt-store out ; state regs -> bufA
    {
      float4_ acc[2][2];
      const half_t* wb = yW_T + (size_t)(w * 32 + c16) * UNITS + q * 8;
      sweepW<2>(wb, [](int i) { return i * 16 * UNITS; }, bufB + c16 * PITCH + q * 8, acc);
#pragma unroll
      for (int cm = 0; cm < 2; ++cm) {
        int col0 = w * 32 + cm * 16 + q * 4;
        float4_ yb4 = *(const float4_*)(s_yb + col0);
#pragma unroll
        for (int rb = 0; rb < 2; ++rb) {
          int row = rb * 16 + c16;
          float4_ yv;
#pragma unroll
          for (int r = 0; r < 4; ++r) yv[r] = fast_tanh(acc[cm][rb][r] + yb4[r]);
          __builtin_nontemporal_store(yv,
              (float4_*)(out + ((size_t)(row0 + row) * DEPTH + s) * ZK + col0));
        }
      }
#pragma unroll
      for (int hh = 0; hh < 2; ++hh)
#pragma unroll
        for (int cm = 0; cm < 2; ++cm) {
          int col0 = hh * 256 + w * 32 + cm * 16 + q * 4;
#pragma unroll
          for (int rb = 0; rb < 2; ++rb)
            *(half4v*)(bufA + (rb * 16 + c16) * PITCH + col0) = state_r[hh][cm][rb];
        }
    }
    __syncthreads();
  }
}

extern "C" void kernel_launch(void* const* d_in, const int* in_sizes, int n_in,
                              void* d_out, int out_size, void* d_ws, size_t ws_size,
                              hipStream_t stream) {
  (void)in_sizes; (void)n_in; (void)out_size; (void)ws_size;
  const float* x   = (const float*)d_in[0];
  const float* h_W = (const float*)d_in[1];
  const float* h_U = (const float*)d_in[2];
  const float* h_b = (const float*)d_in[3];
  const float* f_W = (const float*)d_in[4];
  const float* f_b = (const float*)d_in[5];
  const float* i_W = (const float*)d_in[6];
  const float* i_b = (const float*)d_in[7];
  const float* c_W = (const float*)d_in[8];
  const float* c_b = (const float*)d_in[9];
  const float* o_W = (const float*)d_in[10];
  const float* o_b = (const float*)d_in[11];
  const float* t_W = (const float*)d_in[12];
  const float* t_b = (const float*)d_in[13];
  const float* y_W = (const float*)d_in[14];
  const float* y_b = (const float*)d_in[15];
  const float* h0  = (const float*)d_in[16];
  float* out = (float*)d_out;

  half_t* ws   = (half_t*)d_ws;
  half_t* hW_T = ws;                                   // [512][1024]
  half_t* hU_T = hW_T + (size_t)UNITS * IN_DIM;        // [512][512]
  half_t* W4_T = hU_T + (size_t)UNITS * UNITS;         // [2048][512] f,i,c,o
  half_t* tW_T = W4_T + (size_t)4 * UNITS * UNITS;     // [512][512]
  half_t* yW_T = tW_T + (size_t)UNITS * UNITS;         // [256][512]
  half_t* xh_g = yW_T + (size_t)ZK * UNITS;            // [8192][512]

  const int lds_main = 3 * MT * PITCH * 2 + 2816 * 4;  // bufA,bufB,s_xh + biases
  hipFuncSetAttribute((const void*)xh_kernel, hipFuncAttributeMaxDynamicSharedMemorySize,
                      32 * XPITCH * 2);
  hipFuncSetAttribute((const void*)lstm_main, hipFuncAttributeMaxDynamicSharedMemorySize,
                      lds_main);

  dim3 tb(32, 8);
  hipLaunchKernelGGL(transpose_convert, dim3(UNITS / 32, IN_DIM / 32), tb, 0, stream,
                     h_W, hW_T, IN_DIM, UNITS);
  hipLaunchKernelGGL(transpose_convert, dim3(UNITS / 32, UNITS / 32), tb, 0, stream,
                     h_U, hU_T, UNITS, UNITS);
  hipLaunchKernelGGL(transpose_convert, dim3(UNITS / 32, UNITS / 32), tb, 0, stream,
                     f_W, W4_T + 0 * (size_t)UNITS * UNITS, UNITS, UNITS);
  hipLaunchKernelGGL(transpose_convert, dim3(UNITS / 32, UNITS / 32), tb, 0, stream,
                     i_W, W4_T + 1 * (size_t)UNITS * UNITS, UNITS, UNITS);
  hipLaunchKernelGGL(transpose_convert, dim3(UNITS / 32, UNITS / 32), tb, 0, stream,
                     c_W, W4_T + 2 * (size_t)UNITS * UNITS, UNITS, UNITS);
  hipLaunchKernelGGL(transpose_convert, dim3(UNITS / 32, UNITS / 32), tb, 0, stream,
                     o_W, W4_T + 3 * (size_t)UNITS * UNITS, UNITS, UNITS);
  hipLaunchKernelGGL(transpose_convert, dim3(UNITS / 32, UNITS / 32), tb, 0, stream,
                     t_W, tW_T, UNITS, UNITS);
  hipLaunchKernelGGL(transpose_convert, dim3(ZK / 32, UNITS / 32), tb, 0, stream,
                     y_W, yW_T, UNITS, ZK);
  hipLaunchKernelGGL(xh_kernel, dim3(NROWS / 32), dim3(512), 32 * XPITCH * 2, stream,
                     x, hW_T, h_b, xh_g);
  hipLaunchKernelGGL(lstm_main, dim3(NROWS / MT), dim3(512), lds_main, stream,
                     xh_g, hU_T, W4_T, tW_T, yW_T, f_b, i_b, c_b, o_b, t_b, y_b, h0, out);
}